// Round 4
// baseline (376.490 us; speedup 1.0000x reference)
//
#include <hip/hip_runtime.h>

#define DIN 128
#define H1  64
#define H2  32

// ---- degree count (int), int4-vectorized edge reads ----
__global__ void k_deg(const int* __restrict__ dst, int* __restrict__ degi, int E) {
    int i = blockIdx.x * blockDim.x + threadIdx.x;
    int stride = gridDim.x * blockDim.x;
    int E4 = E >> 2;
    for (int v = i; v < E4; v += stride) {
        int4 d = ((const int4*)dst)[v];
        atomicAdd(&degi[d.x], 1);
        atomicAdd(&degi[d.y], 1);
        atomicAdd(&degi[d.z], 1);
        atomicAdd(&degi[d.w], 1);
    }
    for (int e = E4 * 4 + i; e < E; e += stride) atomicAdd(&degi[dst[e]], 1);
}

// ---- scan step 1: per-block (1024 elems) exclusive scan + block totals ----
__global__ __launch_bounds__(256) void k_scan1(const int* __restrict__ degi,
        int* __restrict__ rowptr, int* __restrict__ partial, int N) {
    int tid = threadIdx.x;
    int base = blockIdx.x * 1024 + tid * 4;
    int v0 = (base + 0 < N) ? degi[base + 0] : 0;
    int v1 = (base + 1 < N) ? degi[base + 1] : 0;
    int v2 = (base + 2 < N) ? degi[base + 2] : 0;
    int v3 = (base + 3 < N) ? degi[base + 3] : 0;
    int sum = v0 + v1 + v2 + v3;
    int lane = tid & 63, wid = tid >> 6;
    int x = sum;
#pragma unroll
    for (int off = 1; off < 64; off <<= 1) {
        int y = __shfl_up(x, off, 64);
        if (lane >= off) x += y;
    }
    __shared__ int wsum[4];
    if (lane == 63) wsum[wid] = x;
    __syncthreads();
    int wbase = 0;
    for (int w = 0; w < wid; ++w) wbase += wsum[w];
    int excl = wbase + x - sum;
    if (base + 0 < N) rowptr[base + 0] = excl;
    if (base + 1 < N) rowptr[base + 1] = excl + v0;
    if (base + 2 < N) rowptr[base + 2] = excl + v0 + v1;
    if (base + 3 < N) rowptr[base + 3] = excl + v0 + v1 + v2;
    if (tid == 0) partial[blockIdx.x] = wsum[0] + wsum[1] + wsum[2] + wsum[3];
}

// ---- scan step 2: one-block exclusive scan of the block totals (nb <= 128) ----
__global__ __launch_bounds__(128) void k_scan2(int* __restrict__ partial, int nb) {
    int tid = threadIdx.x;
    int v = (tid < nb) ? partial[tid] : 0;
    __shared__ int tmp[128];
    tmp[tid] = v;
    __syncthreads();
    for (int off = 1; off < 128; off <<= 1) {
        int y = (tid >= off) ? tmp[tid - off] : 0;
        __syncthreads();
        tmp[tid] += y;
        __syncthreads();
    }
    if (tid < nb) partial[tid] = tmp[tid] - v;   // exclusive
}

// ---- scan step 3: add block offsets; cursor = rowptr; dinv = rsqrt(deg+1) ----
__global__ void k_scan3(int* __restrict__ rowptr, int* __restrict__ cursor,
                        const int* __restrict__ partial, const int* __restrict__ degi,
                        float* __restrict__ dinv, int N) {
    int i = blockIdx.x * blockDim.x + threadIdx.x;
    if (i < N) {
        int v = rowptr[i] + partial[i >> 10];
        rowptr[i] = v; cursor[i] = v;
        dinv[i] = rsqrtf((float)degi[i] + 1.0f);
    }
}

// ---- CSR fill: csr_src[cursor[dst]++] = src  (atomicExch store: 4B write-through,
//      avoids 64B-line write amplification of plain scattered stores) ----
__global__ void k_fill(const int* __restrict__ src, const int* __restrict__ dst,
                       int* __restrict__ cursor, int* __restrict__ csr_src, int E) {
    int i = blockIdx.x * blockDim.x + threadIdx.x;
    int stride = gridDim.x * blockDim.x;
    for (; i < E; i += stride) {
        int d = dst[i];
        int pos = atomicAdd(&cursor[d], 1);
        atomicExch(&csr_src[pos], src[i]);
    }
}

// ---- register-blocked GEMM: out = (op(in) @ W) * dinv rowwise ----
template <int K, int COLS, bool RELU>
__global__ __launch_bounds__(256) void k_gemm(const float* __restrict__ in,
        const float* __restrict__ W, const float* __restrict__ dinv,
        float* __restrict__ outp, int N) {
    constexpr int TX  = COLS / 4;
    constexpr int TY  = 256 / TX;
    constexpr int RPT = 64 / TY;
    constexpr int XS  = K + 4;
    __shared__ float sW[K * COLS];
    __shared__ float sx[64 * XS];
    int tid = threadIdx.x;
    for (int i = tid; i < K * COLS / 4; i += 256)
        *(float4*)&sW[i * 4] = *(const float4*)&W[i * 4];
    int row0 = blockIdx.x * 64;
    constexpr int F4R = K / 4;
    for (int i = tid; i < 64 * F4R; i += 256) {
        int r = i / F4R, c4 = i % F4R;
        int row = row0 + r;
        float4 v = make_float4(0.f, 0.f, 0.f, 0.f);
        if (row < N) {
            v = *(const float4*)&in[(size_t)row * K + c4 * 4];
            if (RELU) {
                v.x = fmaxf(v.x, 0.f); v.y = fmaxf(v.y, 0.f);
                v.z = fmaxf(v.z, 0.f); v.w = fmaxf(v.w, 0.f);
            }
        }
        *(float4*)&sx[r * XS + c4 * 4] = v;
    }
    __syncthreads();
    int tx = tid % TX, ty = tid / TX;
    int c0 = tx * 4, r0 = ty * RPT;
    float acc[RPT][4] = {};
#pragma unroll 2
    for (int kk = 0; kk < K / 4; ++kk) {
        float b[4][4];
#pragma unroll
        for (int u = 0; u < 4; ++u)
            *(float4*)b[u] = *(const float4*)&sW[(kk * 4 + u) * COLS + c0];
        float a[RPT][4];
#pragma unroll
        for (int r = 0; r < RPT; ++r)
            *(float4*)a[r] = *(const float4*)&sx[(r0 + r) * XS + kk * 4];
#pragma unroll
        for (int r = 0; r < RPT; ++r)
#pragma unroll
            for (int u = 0; u < 4; ++u)
#pragma unroll
                for (int c = 0; c < 4; ++c)
                    acc[r][c] = fmaf(a[r][u], b[u][c], acc[r][c]);
    }
#pragma unroll
    for (int r = 0; r < RPT; ++r) {
        int row = row0 + r0 + r;
        if (row < N) {
            float d = dinv[row];
            float4 v = make_float4(acc[r][0] * d, acc[r][1] * d,
                                   acc[r][2] * d, acc[r][3] * d);
            *(float4*)&outp[(size_t)row * COLS + c0] = v;
        }
    }
}

// ---- pull aggregation: out[n] = dinv[n] * (t'[n] + sum_{s in CSR(n)} t'[s]) ----
template <int LOGF>
__global__ __launch_bounds__(256) void k_agg(const int* __restrict__ rowptr,
        const int* __restrict__ degi, const int* __restrict__ csr_src,
        const float* __restrict__ dinv, const float* __restrict__ tp,
        float* __restrict__ out, int N) {
    const int F = 1 << LOGF;
    int local = threadIdx.x >> LOGF;
    int j = threadIdx.x & (F - 1);
    int n = blockIdx.x * (256 >> LOGF) + local;
    if (n >= N) return;
    int start = rowptr[n];
    int deg = degi[n];
    float acc = tp[((size_t)n << LOGF) + j];
    int k = 0;
    for (; k + 4 <= deg; k += 4) {
        int s0 = csr_src[start + k + 0];
        int s1 = csr_src[start + k + 1];
        int s2 = csr_src[start + k + 2];
        int s3 = csr_src[start + k + 3];
        acc += tp[((size_t)s0 << LOGF) + j];
        acc += tp[((size_t)s1 << LOGF) + j];
        acc += tp[((size_t)s2 << LOGF) + j];
        acc += tp[((size_t)s3 << LOGF) + j];
    }
    for (; k < deg; ++k) {
        int s = csr_src[start + k];
        acc += tp[((size_t)s << LOGF) + j];
    }
    out[((size_t)n << LOGF) + j] = acc * dinv[n];
}

extern "C" void kernel_launch(void* const* d_in, const int* in_sizes, int n_in,
                              void* d_out, int out_size, void* d_ws, size_t ws_size,
                              hipStream_t stream) {
    const float* x  = (const float*)d_in[0];
    const int*   ei = (const int*)d_in[1];
    const float* W1 = (const float*)d_in[2];
    const float* W2 = (const float*)d_in[3];

    const int N = in_sizes[0] / DIN;   // 100000
    const int E = in_sizes[1] / 2;     // 1600000
    const int* src = ei;
    const int* dst = ei + E;

    float* dinv    = (float*)d_ws;                   // N
    int*   degi    = (int*)(dinv + N);               // N
    int*   rowptr  = degi + N;                       // N
    int*   cursor  = rowptr + N;                     // N
    int*   partial = cursor + N;                     // 256
    int*   csr_src = partial + 256;                  // E
    float* t1p     = (float*)(csr_src + E);          // N*64
    float* agg1    = t1p + (size_t)N * H1;           // N*64
    float* t2p     = t1p;                            // reuse after agg1 built
    float* out     = (float*)d_out;                  // N*32

    const int nb = (N + 1023) / 1024;                // scan blocks (98)

    // --- CSR build ---
    hipMemsetAsync(degi, 0, (size_t)N * sizeof(int), stream);
    k_deg<<<1024, 256, 0, stream>>>(dst, degi, E);
    k_scan1<<<nb, 256, 0, stream>>>(degi, rowptr, partial, N);
    k_scan2<<<1, 128, 0, stream>>>(partial, nb);
    k_scan3<<<(N + 255) / 256, 256, 0, stream>>>(rowptr, cursor, partial, degi, dinv, N);
    k_fill<<<2048, 256, 0, stream>>>(src, dst, cursor, csr_src, E);

    const int ntile = (N + 63) / 64;                 // 1563

    // --- layer 1 ---
    k_gemm<DIN, H1, false><<<ntile, 256, 0, stream>>>(x, W1, dinv, t1p, N);
    k_agg<6><<<(N + 3) / 4, 256, 0, stream>>>(rowptr, degi, csr_src, dinv, t1p, agg1, N);

    // --- layer 2 ---
    k_gemm<H1, H2, true><<<ntile, 256, 0, stream>>>(agg1, W2, dinv, t2p, N);
    k_agg<5><<<(N + 7) / 8, 256, 0, stream>>>(rowptr, degi, csr_src, dinv, t2p, out, N);
}

// Round 5
// 277.039 us; speedup vs baseline: 1.3590x; 1.3590x over previous
//
#include <hip/hip_runtime.h>

#define DIN 128
#define H1  64
#define H2  32
#define NCH 256      // sort chunks
#define BSH 9        // bucket = dst >> BSH (512 nodes/bucket)

// ---- chunk histogram by bucket + global degree count (fused) ----
__global__ __launch_bounds__(256) void k_hist(const int* __restrict__ dst,
        int* __restrict__ degi, int* __restrict__ H, int E, int NB, int chunk) {
    __shared__ int lh[256];
    int c = blockIdx.x, tid = threadIdx.x;
    lh[tid] = 0;
    __syncthreads();
    int e0 = c * chunk, e1 = min(E, e0 + chunk);
    for (int e = e0 + tid; e < e1; e += 256) {
        int d = dst[e];
        atomicAdd(&lh[d >> BSH], 1);
        atomicAdd(&degi[d], 1);
    }
    __syncthreads();
    if (tid < NB) H[tid * NCH + c] = lh[tid];
}

// ---- scan step 1: per-block (1024 elems) exclusive scan + block totals ----
// safe with out == in (each elem read before written by the same thread)
__global__ __launch_bounds__(256) void k_scan1(const int* __restrict__ in,
        int* __restrict__ out, int* __restrict__ partial, int N) {
    int tid = threadIdx.x;
    int base = blockIdx.x * 1024 + tid * 4;
    int v0 = (base + 0 < N) ? in[base + 0] : 0;
    int v1 = (base + 1 < N) ? in[base + 1] : 0;
    int v2 = (base + 2 < N) ? in[base + 2] : 0;
    int v3 = (base + 3 < N) ? in[base + 3] : 0;
    int sum = v0 + v1 + v2 + v3;
    int lane = tid & 63, wid = tid >> 6;
    int x = sum;
#pragma unroll
    for (int off = 1; off < 64; off <<= 1) {
        int y = __shfl_up(x, off, 64);
        if (lane >= off) x += y;
    }
    __shared__ int wsum[4];
    if (lane == 63) wsum[wid] = x;
    __syncthreads();
    int wbase = 0;
    for (int w = 0; w < wid; ++w) wbase += wsum[w];
    int excl = wbase + x - sum;
    if (base + 0 < N) out[base + 0] = excl;
    if (base + 1 < N) out[base + 1] = excl + v0;
    if (base + 2 < N) out[base + 2] = excl + v0 + v1;
    if (base + 3 < N) out[base + 3] = excl + v0 + v1 + v2;
    if (tid == 0) partial[blockIdx.x] = wsum[0] + wsum[1] + wsum[2] + wsum[3];
}

// ---- scan step 2: one-block exclusive scan of block totals (nb <= 128) ----
__global__ __launch_bounds__(128) void k_scan2(int* __restrict__ partial, int nb) {
    int tid = threadIdx.x;
    int v = (tid < nb) ? partial[tid] : 0;
    __shared__ int tmp[128];
    tmp[tid] = v;
    __syncthreads();
    for (int off = 1; off < 128; off <<= 1) {
        int y = (tid >= off) ? tmp[tid - off] : 0;
        __syncthreads();
        tmp[tid] += y;
        __syncthreads();
    }
    if (tid < nb) partial[tid] = tmp[tid] - v;   // exclusive
}

// ---- scan step 3 (rowptr variant): add block offsets + dinv ----
__global__ void k_scan3(int* __restrict__ rowptr, const int* __restrict__ partial,
                        const int* __restrict__ degi, float* __restrict__ dinv, int N) {
    int i = blockIdx.x * blockDim.x + threadIdx.x;
    if (i < N) {
        rowptr[i] += partial[i >> 10];
        dinv[i] = rsqrtf((float)degi[i] + 1.0f);
    }
}

// ---- scan step 3 (plain variant, for H) ----
__global__ void k_scan3b(int* __restrict__ a, const int* __restrict__ partial, int n) {
    int i = blockIdx.x * blockDim.x + threadIdx.x;
    if (i < n) a[i] += partial[i >> 10];
}

// ---- bucket sort: chunk c writes its edges into bucket-grouped ep ----
__global__ __launch_bounds__(256) void k_bsort(const int* __restrict__ src,
        const int* __restrict__ dst, const int* __restrict__ H,
        int2* __restrict__ ep, int E, int NB, int chunk) {
    __shared__ int cur[256];
    int c = blockIdx.x, tid = threadIdx.x;
    for (int b = tid; b < NB; b += 256) cur[b] = H[b * NCH + c];
    __syncthreads();
    int e0 = c * chunk, e1 = min(E, e0 + chunk);
    for (int e = e0 + tid; e < e1; e += 256) {
        int s = src[e], d = dst[e];
        int pos = atomicAdd(&cur[d >> BSH], 1);
        ep[pos] = make_int2(s, d);
    }
}

// ---- final CSR fill: one block per bucket, LDS cursors, local writes ----
__global__ __launch_bounds__(256) void k_fill2(const int2* __restrict__ ep,
        const int* __restrict__ H, const int* __restrict__ rowptr,
        int* __restrict__ csr_src, int E, int N, int NB) {
    __shared__ int cur[1 << BSH];
    int b = blockIdx.x, tid = threadIdx.x;
    int base = b << BSH;
    for (int i = tid; i < (1 << BSH); i += 256) {
        int n = base + i;
        cur[i] = (n < N) ? rowptr[n] : 0;
    }
    int bstart = H[b * NCH];
    int bend = (b + 1 < NB) ? H[(b + 1) * NCH] : E;
    __syncthreads();
    for (int e = bstart + tid; e < bend; e += 256) {
        int2 p = ep[e];
        int pos = atomicAdd(&cur[p.y - base], 1);
        csr_src[pos] = p.x;
    }
}

// ---- register-blocked GEMM: out = (op(in) @ W) * dinv rowwise ----
template <int K, int COLS, bool RELU>
__global__ __launch_bounds__(256) void k_gemm(const float* __restrict__ in,
        const float* __restrict__ W, const float* __restrict__ dinv,
        float* __restrict__ outp, int N) {
    constexpr int TX  = COLS / 4;
    constexpr int TY  = 256 / TX;
    constexpr int RPT = 64 / TY;
    constexpr int XS  = K + 4;
    __shared__ float sW[K * COLS];
    __shared__ float sx[64 * XS];
    int tid = threadIdx.x;
    for (int i = tid; i < K * COLS / 4; i += 256)
        *(float4*)&sW[i * 4] = *(const float4*)&W[i * 4];
    int row0 = blockIdx.x * 64;
    constexpr int F4R = K / 4;
    for (int i = tid; i < 64 * F4R; i += 256) {
        int r = i / F4R, c4 = i % F4R;
        int row = row0 + r;
        float4 v = make_float4(0.f, 0.f, 0.f, 0.f);
        if (row < N) {
            v = *(const float4*)&in[(size_t)row * K + c4 * 4];
            if (RELU) {
                v.x = fmaxf(v.x, 0.f); v.y = fmaxf(v.y, 0.f);
                v.z = fmaxf(v.z, 0.f); v.w = fmaxf(v.w, 0.f);
            }
        }
        *(float4*)&sx[r * XS + c4 * 4] = v;
    }
    __syncthreads();
    int tx = tid % TX, ty = tid / TX;
    int c0 = tx * 4, r0 = ty * RPT;
    float acc[RPT][4] = {};
#pragma unroll 2
    for (int kk = 0; kk < K / 4; ++kk) {
        float b[4][4];
#pragma unroll
        for (int u = 0; u < 4; ++u)
            *(float4*)b[u] = *(const float4*)&sW[(kk * 4 + u) * COLS + c0];
        float a[RPT][4];
#pragma unroll
        for (int r = 0; r < RPT; ++r)
            *(float4*)a[r] = *(const float4*)&sx[(r0 + r) * XS + kk * 4];
#pragma unroll
        for (int r = 0; r < RPT; ++r)
#pragma unroll
            for (int u = 0; u < 4; ++u)
#pragma unroll
                for (int c = 0; c < 4; ++c)
                    acc[r][c] = fmaf(a[r][u], b[u][c], acc[r][c]);
    }
#pragma unroll
    for (int r = 0; r < RPT; ++r) {
        int row = row0 + r0 + r;
        if (row < N) {
            float d = dinv[row];
            float4 v = make_float4(acc[r][0] * d, acc[r][1] * d,
                                   acc[r][2] * d, acc[r][3] * d);
            *(float4*)&outp[(size_t)row * COLS + c0] = v;
        }
    }
}

// ---- pull aggregation: out[n] = dinv[n] * (t'[n] + sum_{s in CSR(n)} t'[s]) ----
template <int LOGF>
__global__ __launch_bounds__(256) void k_agg(const int* __restrict__ rowptr,
        const int* __restrict__ degi, const int* __restrict__ csr_src,
        const float* __restrict__ dinv, const float* __restrict__ tp,
        float* __restrict__ out, int N) {
    const int F = 1 << LOGF;
    int local = threadIdx.x >> LOGF;
    int j = threadIdx.x & (F - 1);
    int n = blockIdx.x * (256 >> LOGF) + local;
    if (n >= N) return;
    int start = rowptr[n];
    int deg = degi[n];
    float acc = tp[((size_t)n << LOGF) + j];
    int k = 0;
    for (; k + 4 <= deg; k += 4) {
        int s0 = csr_src[start + k + 0];
        int s1 = csr_src[start + k + 1];
        int s2 = csr_src[start + k + 2];
        int s3 = csr_src[start + k + 3];
        acc += tp[((size_t)s0 << LOGF) + j];
        acc += tp[((size_t)s1 << LOGF) + j];
        acc += tp[((size_t)s2 << LOGF) + j];
        acc += tp[((size_t)s3 << LOGF) + j];
    }
    for (; k < deg; ++k) {
        int s = csr_src[start + k];
        acc += tp[((size_t)s << LOGF) + j];
    }
    out[((size_t)n << LOGF) + j] = acc * dinv[n];
}

extern "C" void kernel_launch(void* const* d_in, const int* in_sizes, int n_in,
                              void* d_out, int out_size, void* d_ws, size_t ws_size,
                              hipStream_t stream) {
    const float* x  = (const float*)d_in[0];
    const int*   ei = (const int*)d_in[1];
    const float* W1 = (const float*)d_in[2];
    const float* W2 = (const float*)d_in[3];

    const int N = in_sizes[0] / DIN;   // 100000
    const int E = in_sizes[1] / 2;     // 1600000
    const int* src = ei;
    const int* dst = ei + E;

    const int NB    = (N + (1 << BSH) - 1) >> BSH;   // 196 buckets
    const int NBNCH = NB * NCH;                       // 50176
    const int chunk = (E + NCH - 1) / NCH;            // 6250

    // workspace layout (4-byte elems)
    float* dinv    = (float*)d_ws;                   // N
    int*   degi    = (int*)(dinv + N);               // N
    int*   rowptr  = degi + N;                       // N
    int*   H       = rowptr + N;                     // NB*NCH (<= N)
    int*   partial = H + N;                          // 256
    int*   csr_src = partial + 256;                  // E
    float* t1p     = (float*)(csr_src + E);          // N*64
    float* agg1    = t1p + (size_t)N * H1;           // N*64
    float* t2p     = t1p;                            // reuse after agg1 built
    float* out     = (float*)d_out;                  // N*32
    int2*  ep      = (int2*)t1p;                     // 2E ints, consumed pre-gemm1

    // --- counting-sort CSR build ---
    hipMemsetAsync(degi, 0, (size_t)N * sizeof(int), stream);
    k_hist<<<NCH, 256, 0, stream>>>(dst, degi, H, E, NB, chunk);
    k_scan1<<<(NBNCH + 1023) / 1024, 256, 0, stream>>>(H, H, partial, NBNCH);
    k_scan2<<<1, 128, 0, stream>>>(partial, (NBNCH + 1023) / 1024);
    k_scan3b<<<(NBNCH + 255) / 256, 256, 0, stream>>>(H, partial, NBNCH);
    k_scan1<<<(N + 1023) / 1024, 256, 0, stream>>>(degi, rowptr, partial, N);
    k_scan2<<<1, 128, 0, stream>>>(partial, (N + 1023) / 1024);
    k_scan3<<<(N + 255) / 256, 256, 0, stream>>>(rowptr, partial, degi, dinv, N);
    k_bsort<<<NCH, 256, 0, stream>>>(src, dst, H, ep, E, NB, chunk);
    k_fill2<<<NB, 256, 0, stream>>>(ep, H, rowptr, csr_src, E, N, NB);

    const int ntile = (N + 63) / 64;

    // --- layer 1 ---
    k_gemm<DIN, H1, false><<<ntile, 256, 0, stream>>>(x, W1, dinv, t1p, N);
    k_agg<6><<<(N + 3) / 4, 256, 0, stream>>>(rowptr, degi, csr_src, dinv, t1p, agg1, N);

    // --- layer 2 ---
    k_gemm<H1, H2, true><<<ntile, 256, 0, stream>>>(agg1, W2, dinv, t2p, N);
    k_agg<5><<<(N + 7) / 8, 256, 0, stream>>>(rowptr, degi, csr_src, dinv, t2p, out, N);
}

// Round 6
// 234.967 us; speedup vs baseline: 1.6023x; 1.1791x over previous
//
#include <hip/hip_runtime.h>
#include <hip/hip_fp16.h>

#define DIN 128
#define H1  64
#define H2  32
#define NCH 256      // sort chunks
#define BSH 9        // bucket = dst >> BSH (512 nodes/bucket)

// ---- chunk histogram by bucket + global degree count (fused) ----
__global__ __launch_bounds__(256) void k_hist(const int* __restrict__ dst,
        int* __restrict__ degi, int* __restrict__ H, int E, int NB, int chunk) {
    __shared__ int lh[256];
    int c = blockIdx.x, tid = threadIdx.x;
    lh[tid] = 0;
    __syncthreads();
    int e0 = c * chunk, e1 = min(E, e0 + chunk);
    for (int e = e0 + tid; e < e1; e += 256) {
        int d = dst[e];
        atomicAdd(&lh[d >> BSH], 1);
        atomicAdd(&degi[d], 1);
    }
    __syncthreads();
    if (tid < NB) H[tid * NCH + c] = lh[tid];
}

// ---- scan step 1: per-block (1024 elems) exclusive scan + block totals ----
__global__ __launch_bounds__(256) void k_scan1(const int* __restrict__ in,
        int* __restrict__ out, int* __restrict__ partial, int N) {
    int tid = threadIdx.x;
    int base = blockIdx.x * 1024 + tid * 4;
    int v0 = (base + 0 < N) ? in[base + 0] : 0;
    int v1 = (base + 1 < N) ? in[base + 1] : 0;
    int v2 = (base + 2 < N) ? in[base + 2] : 0;
    int v3 = (base + 3 < N) ? in[base + 3] : 0;
    int sum = v0 + v1 + v2 + v3;
    int lane = tid & 63, wid = tid >> 6;
    int x = sum;
#pragma unroll
    for (int off = 1; off < 64; off <<= 1) {
        int y = __shfl_up(x, off, 64);
        if (lane >= off) x += y;
    }
    __shared__ int wsum[4];
    if (lane == 63) wsum[wid] = x;
    __syncthreads();
    int wbase = 0;
    for (int w = 0; w < wid; ++w) wbase += wsum[w];
    int excl = wbase + x - sum;
    if (base + 0 < N) out[base + 0] = excl;
    if (base + 1 < N) out[base + 1] = excl + v0;
    if (base + 2 < N) out[base + 2] = excl + v0 + v1;
    if (base + 3 < N) out[base + 3] = excl + v0 + v1 + v2;
    if (tid == 0) partial[blockIdx.x] = wsum[0] + wsum[1] + wsum[2] + wsum[3];
}

// ---- scan step 2: one-block exclusive scan of block totals (nb <= 128) ----
__global__ __launch_bounds__(128) void k_scan2(int* __restrict__ partial, int nb) {
    int tid = threadIdx.x;
    int v = (tid < nb) ? partial[tid] : 0;
    __shared__ int tmp[128];
    tmp[tid] = v;
    __syncthreads();
    for (int off = 1; off < 128; off <<= 1) {
        int y = (tid >= off) ? tmp[tid - off] : 0;
        __syncthreads();
        tmp[tid] += y;
        __syncthreads();
    }
    if (tid < nb) partial[tid] = tmp[tid] - v;   // exclusive
}

// ---- scan step 3 (rowptr variant): add block offsets + dinv ----
__global__ void k_scan3(int* __restrict__ rowptr, const int* __restrict__ partial,
                        const int* __restrict__ degi, float* __restrict__ dinv, int N) {
    int i = blockIdx.x * blockDim.x + threadIdx.x;
    if (i < N) {
        rowptr[i] += partial[i >> 10];
        dinv[i] = rsqrtf((float)degi[i] + 1.0f);
    }
}

// ---- scan step 3 (plain variant, for H) ----
__global__ void k_scan3b(int* __restrict__ a, const int* __restrict__ partial, int n) {
    int i = blockIdx.x * blockDim.x + threadIdx.x;
    if (i < n) a[i] += partial[i >> 10];
}

// ---- bucket sort: chunk c writes its edges into bucket-grouped ep ----
__global__ __launch_bounds__(256) void k_bsort(const int* __restrict__ src,
        const int* __restrict__ dst, const int* __restrict__ H,
        int2* __restrict__ ep, int E, int NB, int chunk) {
    __shared__ int cur[256];
    int c = blockIdx.x, tid = threadIdx.x;
    for (int b = tid; b < NB; b += 256) cur[b] = H[b * NCH + c];
    __syncthreads();
    int e0 = c * chunk, e1 = min(E, e0 + chunk);
    for (int e = e0 + tid; e < e1; e += 256) {
        int s = src[e], d = dst[e];
        int pos = atomicAdd(&cur[d >> BSH], 1);
        ep[pos] = make_int2(s, d);
    }
}

// ---- final CSR fill: one block per bucket, LDS cursors, local writes ----
__global__ __launch_bounds__(256) void k_fill2(const int2* __restrict__ ep,
        const int* __restrict__ H, const int* __restrict__ rowptr,
        int* __restrict__ csr_src, int E, int N, int NB) {
    __shared__ int cur[1 << BSH];
    int b = blockIdx.x, tid = threadIdx.x;
    int base = b << BSH;
    for (int i = tid; i < (1 << BSH); i += 256) {
        int n = base + i;
        cur[i] = (n < N) ? rowptr[n] : 0;
    }
    int bstart = H[b * NCH];
    int bend = (b + 1 < NB) ? H[(b + 1) * NCH] : E;
    __syncthreads();
    for (int e = bstart + tid; e < bend; e += 256) {
        int2 p = ep[e];
        int pos = atomicAdd(&cur[p.y - base], 1);
        csr_src[pos] = p.x;
    }
}

// ---- register-blocked GEMM: outp(fp16) = (op(in) @ W) * dinv rowwise ----
template <int K, int COLS, bool RELU>
__global__ __launch_bounds__(256) void k_gemm(const float* __restrict__ in,
        const float* __restrict__ W, const float* __restrict__ dinv,
        __half* __restrict__ outp, int N) {
    constexpr int TX  = COLS / 4;
    constexpr int TY  = 256 / TX;
    constexpr int RPT = 64 / TY;
    constexpr int XS  = K + 4;
    __shared__ float sW[K * COLS];
    __shared__ float sx[64 * XS];
    int tid = threadIdx.x;
    for (int i = tid; i < K * COLS / 4; i += 256)
        *(float4*)&sW[i * 4] = *(const float4*)&W[i * 4];
    int row0 = blockIdx.x * 64;
    constexpr int F4R = K / 4;
    for (int i = tid; i < 64 * F4R; i += 256) {
        int r = i / F4R, c4 = i % F4R;
        int row = row0 + r;
        float4 v = make_float4(0.f, 0.f, 0.f, 0.f);
        if (row < N) {
            v = *(const float4*)&in[(size_t)row * K + c4 * 4];
            if (RELU) {
                v.x = fmaxf(v.x, 0.f); v.y = fmaxf(v.y, 0.f);
                v.z = fmaxf(v.z, 0.f); v.w = fmaxf(v.w, 0.f);
            }
        }
        *(float4*)&sx[r * XS + c4 * 4] = v;
    }
    __syncthreads();
    int tx = tid % TX, ty = tid / TX;
    int c0 = tx * 4, r0 = ty * RPT;
    float acc[RPT][4] = {};
#pragma unroll 2
    for (int kk = 0; kk < K / 4; ++kk) {
        float b[4][4];
#pragma unroll
        for (int u = 0; u < 4; ++u)
            *(float4*)b[u] = *(const float4*)&sW[(kk * 4 + u) * COLS + c0];
        float a[RPT][4];
#pragma unroll
        for (int r = 0; r < RPT; ++r)
            *(float4*)a[r] = *(const float4*)&sx[(r0 + r) * XS + kk * 4];
#pragma unroll
        for (int r = 0; r < RPT; ++r)
#pragma unroll
            for (int u = 0; u < 4; ++u)
#pragma unroll
                for (int c = 0; c < 4; ++c)
                    acc[r][c] = fmaf(a[r][u], b[u][c], acc[r][c]);
    }
#pragma unroll
    for (int r = 0; r < RPT; ++r) {
        int row = row0 + r0 + r;
        if (row < N) {
            float d = dinv[row];
            __half2 h0 = __floats2half2_rn(acc[r][0] * d, acc[r][1] * d);
            __half2 h1 = __floats2half2_rn(acc[r][2] * d, acc[r][3] * d);
            __half2* o2 = (__half2*)&outp[(size_t)row * COLS + c0];
            o2[0] = h0;
            o2[1] = h1;
        }
    }
}

// ---- pull aggregation (fp16 table, fp32 accum):
//      out[n] = dinv[n] * (t'[n] + sum_{s in CSR(n)} t'[s]) ----
template <int LOGF2>   // half2 elems per node row (5 -> 64 feats, 4 -> 32 feats)
__global__ __launch_bounds__(256) void k_aggh(const int* __restrict__ rowptr,
        const int* __restrict__ degi, const int* __restrict__ csr_src,
        const float* __restrict__ dinv, const __half2* __restrict__ tp,
        float2* __restrict__ out, int N) {
    const int F2 = 1 << LOGF2;
    int local = threadIdx.x >> LOGF2;
    int j = threadIdx.x & (F2 - 1);
    int n = blockIdx.x * (256 >> LOGF2) + local;
    if (n >= N) return;
    int start = rowptr[n];
    int deg = degi[n];
    float2 f = __half22float2(tp[((size_t)n << LOGF2) + j]);   // self term
    float ax = f.x, ay = f.y;
    int k = 0;
    for (; k + 4 <= deg; k += 4) {
        int s0 = csr_src[start + k + 0];
        int s1 = csr_src[start + k + 1];
        int s2 = csr_src[start + k + 2];
        int s3 = csr_src[start + k + 3];
        float2 f0 = __half22float2(tp[((size_t)s0 << LOGF2) + j]);
        float2 f1 = __half22float2(tp[((size_t)s1 << LOGF2) + j]);
        float2 f2 = __half22float2(tp[((size_t)s2 << LOGF2) + j]);
        float2 f3 = __half22float2(tp[((size_t)s3 << LOGF2) + j]);
        ax += f0.x + f1.x + f2.x + f3.x;
        ay += f0.y + f1.y + f2.y + f3.y;
    }
    for (; k < deg; ++k) {
        int s = csr_src[start + k];
        float2 f0 = __half22float2(tp[((size_t)s << LOGF2) + j]);
        ax += f0.x; ay += f0.y;
    }
    float dv = dinv[n];
    out[((size_t)n << LOGF2) + j] = make_float2(ax * dv, ay * dv);
}

extern "C" void kernel_launch(void* const* d_in, const int* in_sizes, int n_in,
                              void* d_out, int out_size, void* d_ws, size_t ws_size,
                              hipStream_t stream) {
    const float* x  = (const float*)d_in[0];
    const int*   ei = (const int*)d_in[1];
    const float* W1 = (const float*)d_in[2];
    const float* W2 = (const float*)d_in[3];

    const int N = in_sizes[0] / DIN;   // 100000
    const int E = in_sizes[1] / 2;     // 1600000
    const int* src = ei;
    const int* dst = ei + E;

    const int NB    = (N + (1 << BSH) - 1) >> BSH;   // 196 buckets
    const int NBNCH = NB * NCH;                       // 50176
    const int chunk = (E + NCH - 1) / NCH;            // 6250

    // workspace layout
    float*  dinv    = (float*)d_ws;                   // N
    int*    degi    = (int*)(dinv + N);               // N
    int*    rowptr  = degi + N;                       // N
    int*    H       = rowptr + N;                     // NB*NCH (<= N)
    int*    partial = H + N;                          // 256
    int*    csr_src = partial + 256;                  // E
    __half* t1h     = (__half*)(csr_src + E);         // N*64 halves (12.8 MB)
    float*  agg1    = (float*)(t1h + (size_t)N * H1); // N*64 fp32  (25.6 MB)
    __half* t2h     = t1h;                            // reuse after agg1 built
    float*  out     = (float*)d_out;                  // N*32 fp32
    int2*   ep      = (int2*)agg1;                    // E int2, consumed by k_fill2
                                                      // before agg1 is written

    // --- counting-sort CSR build ---
    hipMemsetAsync(degi, 0, (size_t)N * sizeof(int), stream);
    k_hist<<<NCH, 256, 0, stream>>>(dst, degi, H, E, NB, chunk);
    k_scan1<<<(NBNCH + 1023) / 1024, 256, 0, stream>>>(H, H, partial, NBNCH);
    k_scan2<<<1, 128, 0, stream>>>(partial, (NBNCH + 1023) / 1024);
    k_scan3b<<<(NBNCH + 255) / 256, 256, 0, stream>>>(H, partial, NBNCH);
    k_scan1<<<(N + 1023) / 1024, 256, 0, stream>>>(degi, rowptr, partial, N);
    k_scan2<<<1, 128, 0, stream>>>(partial, (N + 1023) / 1024);
    k_scan3<<<(N + 255) / 256, 256, 0, stream>>>(rowptr, partial, degi, dinv, N);
    k_bsort<<<NCH, 256, 0, stream>>>(src, dst, H, ep, E, NB, chunk);
    k_fill2<<<NB, 256, 0, stream>>>(ep, H, rowptr, csr_src, E, N, NB);

    const int ntile = (N + 63) / 64;

    // --- layer 1 ---
    k_gemm<DIN, H1, false><<<ntile, 256, 0, stream>>>(x, W1, dinv, t1h, N);
    k_aggh<5><<<(N + 7) / 8, 256, 0, stream>>>(rowptr, degi, csr_src, dinv,
                                               (const __half2*)t1h, (float2*)agg1, N);

    // --- layer 2 ---
    k_gemm<H1, H2, true><<<ntile, 256, 0, stream>>>(agg1, W2, dinv, t2h, N);
    k_aggh<4><<<(N + 15) / 16, 256, 0, stream>>>(rowptr, degi, csr_src, dinv,
                                                 (const __half2*)t2h, (float2*)out, N);
}

// Round 7
// 167.845 us; speedup vs baseline: 2.2431x; 1.3999x over previous
//
#include <hip/hip_runtime.h>
#include <hip/hip_fp16.h>

#define DIN 128
#define H1  64
#define H2  32
#define NCH 512      // sort chunks
#define BSH 8        // bucket = dst >> BSH (256 nodes/bucket)

// ---- chunk histogram by bucket (LDS only, no global atomics) ----
__global__ __launch_bounds__(256) void k_hist(const int* __restrict__ dst,
        int* __restrict__ H, int E, int NB, int chunk) {
    __shared__ int lh[512];
    int c = blockIdx.x, tid = threadIdx.x;
    for (int b = tid; b < NB; b += 256) lh[b] = 0;
    __syncthreads();
    int e0 = c * chunk, e1 = min(E, e0 + chunk);
    for (int e = e0 + tid; e < e1; e += 256)
        atomicAdd(&lh[dst[e] >> BSH], 1);
    __syncthreads();
    for (int b = tid; b < NB; b += 256) H[(size_t)b * NCH + c] = lh[b];
}

// ---- scan step 1: per-block (1024 elems) exclusive scan + block totals ----
// safe with out == in (each elem read before written by the same thread)
__global__ __launch_bounds__(256) void k_scan1(const int* __restrict__ in,
        int* __restrict__ out, int* __restrict__ partial, int N) {
    int tid = threadIdx.x;
    int base = blockIdx.x * 1024 + tid * 4;
    int v0 = (base + 0 < N) ? in[base + 0] : 0;
    int v1 = (base + 1 < N) ? in[base + 1] : 0;
    int v2 = (base + 2 < N) ? in[base + 2] : 0;
    int v3 = (base + 3 < N) ? in[base + 3] : 0;
    int sum = v0 + v1 + v2 + v3;
    int lane = tid & 63, wid = tid >> 6;
    int x = sum;
#pragma unroll
    for (int off = 1; off < 64; off <<= 1) {
        int y = __shfl_up(x, off, 64);
        if (lane >= off) x += y;
    }
    __shared__ int wsum[4];
    if (lane == 63) wsum[wid] = x;
    __syncthreads();
    int wbase = 0;
    for (int w = 0; w < wid; ++w) wbase += wsum[w];
    int excl = wbase + x - sum;
    if (base + 0 < N) out[base + 0] = excl;
    if (base + 1 < N) out[base + 1] = excl + v0;
    if (base + 2 < N) out[base + 2] = excl + v0 + v1;
    if (base + 3 < N) out[base + 3] = excl + v0 + v1 + v2;
    if (tid == 0) partial[blockIdx.x] = wsum[0] + wsum[1] + wsum[2] + wsum[3];
}

// ---- scan step 2: one-block exclusive scan of block totals (nb <= 256) ----
__global__ __launch_bounds__(256) void k_scan2(int* __restrict__ partial, int nb) {
    int tid = threadIdx.x;
    int v = (tid < nb) ? partial[tid] : 0;
    __shared__ int tmp[256];
    tmp[tid] = v;
    __syncthreads();
    for (int off = 1; off < 256; off <<= 1) {
        int y = (tid >= off) ? tmp[tid - off] : 0;
        __syncthreads();
        tmp[tid] += y;
        __syncthreads();
    }
    if (tid < nb) partial[tid] = tmp[tid] - v;   // exclusive
}

// ---- scan step 3: add block offsets ----
__global__ void k_scan3b(int* __restrict__ a, const int* __restrict__ partial, int n) {
    int i = blockIdx.x * blockDim.x + threadIdx.x;
    if (i < n) a[i] += partial[i >> 10];
}

// ---- bucket sort: chunk c writes its edges into bucket-grouped ep ----
__global__ __launch_bounds__(256) void k_bsort(const int* __restrict__ src,
        const int* __restrict__ dst, const int* __restrict__ H,
        int2* __restrict__ ep, int E, int NB, int chunk) {
    __shared__ int cur[512];
    int c = blockIdx.x, tid = threadIdx.x;
    for (int b = tid; b < NB; b += 256) cur[b] = H[(size_t)b * NCH + c];
    __syncthreads();
    int e0 = c * chunk, e1 = min(E, e0 + chunk);
    for (int e = e0 + tid; e < e1; e += 256) {
        int s = src[e], d = dst[e];
        int pos = atomicAdd(&cur[d >> BSH], 1);
        ep[pos] = make_int2(s, d);
    }
}

// ---- per-bucket CSR finalize: count degrees (LDS), local scan -> rowptr/degi/
//      dinv, then scatter csr_src through LDS cursors (all writes bucket-local) ----
__global__ __launch_bounds__(256) void k_csr(const int2* __restrict__ ep,
        const int* __restrict__ H, int* __restrict__ degi, int* __restrict__ rowptr,
        float* __restrict__ dinv, int* __restrict__ csr_src, int E, int N, int NB) {
    __shared__ int cnt[256], pos[256], wsum[4];
    int b = blockIdx.x, tid = threadIdx.x;
    int base = b << BSH;
    cnt[tid] = 0;
    int bstart = H[(size_t)b * NCH];
    int bend = (b + 1 < NB) ? H[(size_t)(b + 1) * NCH] : E;
    __syncthreads();
    for (int e = bstart + tid; e < bend; e += 256)
        atomicAdd(&cnt[ep[e].y - base], 1);
    __syncthreads();
    int v = cnt[tid];
    int lane = tid & 63, wid = tid >> 6;
    int x = v;
#pragma unroll
    for (int off = 1; off < 64; off <<= 1) {
        int y = __shfl_up(x, off, 64);
        if (lane >= off) x += y;
    }
    if (lane == 63) wsum[wid] = x;
    __syncthreads();
    int wbase = 0;
    for (int w = 0; w < wid; ++w) wbase += wsum[w];
    int excl = wbase + x - v;            // exclusive local prefix
    int n = base + tid;
    if (n < N) {
        degi[n]   = v;
        dinv[n]   = rsqrtf((float)v + 1.0f);
        rowptr[n] = bstart + excl;
    }
    pos[tid] = bstart + excl;
    __syncthreads();
    for (int e = bstart + tid; e < bend; e += 256) {
        int2 p = ep[e];
        int q = atomicAdd(&pos[p.y - base], 1);
        csr_src[q] = p.x;
    }
}

// ---- register-blocked GEMM: outp(fp16) = (op(in) @ W) * dinv rowwise ----
template <int K, int COLS, bool RELU>
__global__ __launch_bounds__(256) void k_gemm(const float* __restrict__ in,
        const float* __restrict__ W, const float* __restrict__ dinv,
        __half* __restrict__ outp, int N) {
    constexpr int TX  = COLS / 4;
    constexpr int TY  = 256 / TX;
    constexpr int RPT = 64 / TY;
    constexpr int XS  = K + 4;
    __shared__ float sW[K * COLS];
    __shared__ float sx[64 * XS];
    int tid = threadIdx.x;
    for (int i = tid; i < K * COLS / 4; i += 256)
        *(float4*)&sW[i * 4] = *(const float4*)&W[i * 4];
    int row0 = blockIdx.x * 64;
    constexpr int F4R = K / 4;
    for (int i = tid; i < 64 * F4R; i += 256) {
        int r = i / F4R, c4 = i % F4R;
        int row = row0 + r;
        float4 v = make_float4(0.f, 0.f, 0.f, 0.f);
        if (row < N) {
            v = *(const float4*)&in[(size_t)row * K + c4 * 4];
            if (RELU) {
                v.x = fmaxf(v.x, 0.f); v.y = fmaxf(v.y, 0.f);
                v.z = fmaxf(v.z, 0.f); v.w = fmaxf(v.w, 0.f);
            }
        }
        *(float4*)&sx[r * XS + c4 * 4] = v;
    }
    __syncthreads();
    int tx = tid % TX, ty = tid / TX;
    int c0 = tx * 4, r0 = ty * RPT;
    float acc[RPT][4] = {};
#pragma unroll 2
    for (int kk = 0; kk < K / 4; ++kk) {
        float b[4][4];
#pragma unroll
        for (int u = 0; u < 4; ++u)
            *(float4*)b[u] = *(const float4*)&sW[(kk * 4 + u) * COLS + c0];
        float a[RPT][4];
#pragma unroll
        for (int r = 0; r < RPT; ++r)
            *(float4*)a[r] = *(const float4*)&sx[(r0 + r) * XS + kk * 4];
#pragma unroll
        for (int r = 0; r < RPT; ++r)
#pragma unroll
            for (int u = 0; u < 4; ++u)
#pragma unroll
                for (int c = 0; c < 4; ++c)
                    acc[r][c] = fmaf(a[r][u], b[u][c], acc[r][c]);
    }
#pragma unroll
    for (int r = 0; r < RPT; ++r) {
        int row = row0 + r0 + r;
        if (row < N) {
            float d = dinv[row];
            __half2 h0 = __floats2half2_rn(acc[r][0] * d, acc[r][1] * d);
            __half2 h1 = __floats2half2_rn(acc[r][2] * d, acc[r][3] * d);
            __half2* o2 = (__half2*)&outp[(size_t)row * COLS + c0];
            o2[0] = h0;
            o2[1] = h1;
        }
    }
}

// ---- pull aggregation (fp16 table, fp32 accum) ----
template <int LOGF2>   // half2 elems per node row (5 -> 64 feats, 4 -> 32 feats)
__global__ __launch_bounds__(256) void k_aggh(const int* __restrict__ rowptr,
        const int* __restrict__ degi, const int* __restrict__ csr_src,
        const float* __restrict__ dinv, const __half2* __restrict__ tp,
        float2* __restrict__ out, int N) {
    const int F2 = 1 << LOGF2;
    int local = threadIdx.x >> LOGF2;
    int j = threadIdx.x & (F2 - 1);
    int n = blockIdx.x * (256 >> LOGF2) + local;
    if (n >= N) return;
    int start = rowptr[n];
    int deg = degi[n];
    float2 f = __half22float2(tp[((size_t)n << LOGF2) + j]);   // self term
    float ax = f.x, ay = f.y;
    int k = 0;
    for (; k + 4 <= deg; k += 4) {
        int s0 = csr_src[start + k + 0];
        int s1 = csr_src[start + k + 1];
        int s2 = csr_src[start + k + 2];
        int s3 = csr_src[start + k + 3];
        float2 f0 = __half22float2(tp[((size_t)s0 << LOGF2) + j]);
        float2 f1 = __half22float2(tp[((size_t)s1 << LOGF2) + j]);
        float2 f2 = __half22float2(tp[((size_t)s2 << LOGF2) + j]);
        float2 f3 = __half22float2(tp[((size_t)s3 << LOGF2) + j]);
        ax += f0.x + f1.x + f2.x + f3.x;
        ay += f0.y + f1.y + f2.y + f3.y;
    }
    for (; k < deg; ++k) {
        int s = csr_src[start + k];
        float2 f0 = __half22float2(tp[((size_t)s << LOGF2) + j]);
        ax += f0.x; ay += f0.y;
    }
    float dv = dinv[n];
    out[((size_t)n << LOGF2) + j] = make_float2(ax * dv, ay * dv);
}

extern "C" void kernel_launch(void* const* d_in, const int* in_sizes, int n_in,
                              void* d_out, int out_size, void* d_ws, size_t ws_size,
                              hipStream_t stream) {
    const float* x  = (const float*)d_in[0];
    const int*   ei = (const int*)d_in[1];
    const float* W1 = (const float*)d_in[2];
    const float* W2 = (const float*)d_in[3];

    const int N = in_sizes[0] / DIN;   // 100000
    const int E = in_sizes[1] / 2;     // 1600000
    const int* src = ei;
    const int* dst = ei + E;

    const int NB    = (N + (1 << BSH) - 1) >> BSH;   // 391 buckets
    const int NBNCH = NB * NCH;                       // 200192
    const int chunk = (E + NCH - 1) / NCH;            // 3125

    // workspace layout (4-byte elems)
    float*  dinv    = (float*)d_ws;                   // N
    int*    degi    = (int*)(dinv + N);               // N
    int*    rowptr  = degi + N;                       // N
    int*    H       = rowptr + N;                     // NB*NCH
    int*    partial = H + NBNCH;                      // 256
    int*    csr_src = partial + 256;                  // E
    __half* t1h     = (__half*)(csr_src + E);         // N*64 halves (12.8 MB)
    float*  agg1    = (float*)(t1h + (size_t)N * H1); // N*64 fp32  (25.6 MB)
    __half* t2h     = t1h;                            // reuse after agg1 built
    float*  out     = (float*)d_out;                  // N*32 fp32
    int2*   ep      = (int2*)agg1;                    // E int2, consumed by k_csr
                                                      // before agg1 is written

    // --- counting-sort CSR build (no global atomics) ---
    k_hist<<<NCH, 256, 0, stream>>>(dst, H, E, NB, chunk);
    k_scan1<<<(NBNCH + 1023) / 1024, 256, 0, stream>>>(H, H, partial, NBNCH);
    k_scan2<<<1, 256, 0, stream>>>(partial, (NBNCH + 1023) / 1024);
    k_scan3b<<<(NBNCH + 255) / 256, 256, 0, stream>>>(H, partial, NBNCH);
    k_bsort<<<NCH, 256, 0, stream>>>(src, dst, H, ep, E, NB, chunk);
    k_csr<<<NB, 256, 0, stream>>>(ep, H, degi, rowptr, dinv, csr_src, E, N, NB);

    const int ntile = (N + 63) / 64;

    // --- layer 1 ---
    k_gemm<DIN, H1, false><<<ntile, 256, 0, stream>>>(x, W1, dinv, t1h, N);
    k_aggh<5><<<(N + 7) / 8, 256, 0, stream>>>(rowptr, degi, csr_src, dinv,
                                               (const __half2*)t1h, (float2*)agg1, N);

    // --- layer 2 ---
    k_gemm<H1, H2, true><<<ntile, 256, 0, stream>>>(agg1, W2, dinv, t2h, N);
    k_aggh<4><<<(N + 15) / 16, 256, 0, stream>>>(rowptr, degi, csr_src, dinv,
                                                 (const __half2*)t2h, (float2*)out, N);
}

// Round 8
// 141.712 us; speedup vs baseline: 2.6567x; 1.1844x over previous
//
#include <hip/hip_runtime.h>
#include <hip/hip_fp16.h>

#define DIN 128
#define H1  64
#define H2  32
#define NCH 512      // sort chunks
#define BSH 8        // bucket = dst >> BSH (256 nodes/bucket)

typedef _Float16 f16x8 __attribute__((ext_vector_type(8)));
typedef _Float16 f16x4 __attribute__((ext_vector_type(4)));
typedef float    f32x4 __attribute__((ext_vector_type(4)));

// ---- chunk histogram by bucket (LDS only, no global atomics) ----
__global__ __launch_bounds__(256) void k_hist(const int* __restrict__ dst,
        int* __restrict__ H, int E, int NB, int chunk) {
    __shared__ int lh[512];
    int c = blockIdx.x, tid = threadIdx.x;
    for (int b = tid; b < NB; b += 256) lh[b] = 0;
    __syncthreads();
    int e0 = c * chunk, e1 = min(E, e0 + chunk);
    for (int e = e0 + tid; e < e1; e += 256)
        atomicAdd(&lh[dst[e] >> BSH], 1);
    __syncthreads();
    for (int b = tid; b < NB; b += 256) H[(size_t)b * NCH + c] = lh[b];
}

// ---- scan step 1: per-block (1024 elems) exclusive scan + block totals ----
__global__ __launch_bounds__(256) void k_scan1(const int* __restrict__ in,
        int* __restrict__ out, int* __restrict__ partial, int N) {
    int tid = threadIdx.x;
    int base = blockIdx.x * 1024 + tid * 4;
    int v0 = (base + 0 < N) ? in[base + 0] : 0;
    int v1 = (base + 1 < N) ? in[base + 1] : 0;
    int v2 = (base + 2 < N) ? in[base + 2] : 0;
    int v3 = (base + 3 < N) ? in[base + 3] : 0;
    int sum = v0 + v1 + v2 + v3;
    int lane = tid & 63, wid = tid >> 6;
    int x = sum;
#pragma unroll
    for (int off = 1; off < 64; off <<= 1) {
        int y = __shfl_up(x, off, 64);
        if (lane >= off) x += y;
    }
    __shared__ int wsum[4];
    if (lane == 63) wsum[wid] = x;
    __syncthreads();
    int wbase = 0;
    for (int w = 0; w < wid; ++w) wbase += wsum[w];
    int excl = wbase + x - sum;
    if (base + 0 < N) out[base + 0] = excl;
    if (base + 1 < N) out[base + 1] = excl + v0;
    if (base + 2 < N) out[base + 2] = excl + v0 + v1;
    if (base + 3 < N) out[base + 3] = excl + v0 + v1 + v2;
    if (tid == 0) partial[blockIdx.x] = wsum[0] + wsum[1] + wsum[2] + wsum[3];
}

// ---- scan step 2: one-block exclusive scan of block totals (nb <= 256) ----
__global__ __launch_bounds__(256) void k_scan2(int* __restrict__ partial, int nb) {
    int tid = threadIdx.x;
    int v = (tid < nb) ? partial[tid] : 0;
    __shared__ int tmp[256];
    tmp[tid] = v;
    __syncthreads();
    for (int off = 1; off < 256; off <<= 1) {
        int y = (tid >= off) ? tmp[tid - off] : 0;
        __syncthreads();
        tmp[tid] += y;
        __syncthreads();
    }
    if (tid < nb) partial[tid] = tmp[tid] - v;   // exclusive
}

// ---- scan step 3: add block offsets ----
__global__ void k_scan3b(int* __restrict__ a, const int* __restrict__ partial, int n) {
    int i = blockIdx.x * blockDim.x + threadIdx.x;
    if (i < n) a[i] += partial[i >> 10];
}

// ---- bucket sort: chunk c writes its edges into bucket-grouped ep ----
__global__ __launch_bounds__(256) void k_bsort(const int* __restrict__ src,
        const int* __restrict__ dst, const int* __restrict__ H,
        int2* __restrict__ ep, int E, int NB, int chunk) {
    __shared__ int cur[512];
    int c = blockIdx.x, tid = threadIdx.x;
    for (int b = tid; b < NB; b += 256) cur[b] = H[(size_t)b * NCH + c];
    __syncthreads();
    int e0 = c * chunk, e1 = min(E, e0 + chunk);
    for (int e = e0 + tid; e < e1; e += 256) {
        int s = src[e], d = dst[e];
        int pos = atomicAdd(&cur[d >> BSH], 1);
        ep[pos] = make_int2(s, d);
    }
}

// ---- per-bucket CSR finalize ----
__global__ __launch_bounds__(256) void k_csr(const int2* __restrict__ ep,
        const int* __restrict__ H, int* __restrict__ degi, int* __restrict__ rowptr,
        float* __restrict__ dinv, int* __restrict__ csr_src, int E, int N, int NB) {
    __shared__ int cnt[256], pos[256], wsum[4];
    int b = blockIdx.x, tid = threadIdx.x;
    int base = b << BSH;
    cnt[tid] = 0;
    int bstart = H[(size_t)b * NCH];
    int bend = (b + 1 < NB) ? H[(size_t)(b + 1) * NCH] : E;
    __syncthreads();
    for (int e = bstart + tid; e < bend; e += 256)
        atomicAdd(&cnt[ep[e].y - base], 1);
    __syncthreads();
    int v = cnt[tid];
    int lane = tid & 63, wid = tid >> 6;
    int x = v;
#pragma unroll
    for (int off = 1; off < 64; off <<= 1) {
        int y = __shfl_up(x, off, 64);
        if (lane >= off) x += y;
    }
    if (lane == 63) wsum[wid] = x;
    __syncthreads();
    int wbase = 0;
    for (int w = 0; w < wid; ++w) wbase += wsum[w];
    int excl = wbase + x - v;            // exclusive local prefix
    int n = base + tid;
    if (n < N) {
        degi[n]   = v;
        dinv[n]   = rsqrtf((float)v + 1.0f);
        rowptr[n] = bstart + excl;
    }
    pos[tid] = bstart + excl;
    __syncthreads();
    for (int e = bstart + tid; e < bend; e += 256) {
        int2 p = ep[e];
        int q = atomicAdd(&pos[p.y - base], 1);
        csr_src[q] = p.x;
    }
}

// ---- MFMA GEMM layer 1: t1h(fp16) = (x @ W1) * dinv ; M=64,N=64,K=128 ----
__global__ __launch_bounds__(256) void k_mgemm1(const float* __restrict__ x,
        const float* __restrict__ W1, const float* __restrict__ dinv,
        _Float16* __restrict__ t1h, int N) {
    __shared__ _Float16 sA[64 * 128];   // 16 KB, row 256 B, XOR-swizzled
    __shared__ _Float16 sB[64 * 128];   // 16 KB, sB[n][k] = W1[k][n], swizzled
    int tid = threadIdx.x;
    int row0 = blockIdx.x * 64;
    // stage A: x rows -> fp16 (coalesced float4 reads)
#pragma unroll
    for (int i = 0; i < 8; ++i) {
        int idx4 = tid + 256 * i;        // 0..2047 float4 slots
        int r = idx4 >> 5, c4 = idx4 & 31;
        int row = row0 + r;
        float4 v = make_float4(0.f, 0.f, 0.f, 0.f);
        if (row < N) v = *(const float4*)&x[(size_t)row * DIN + c4 * 4];
        f16x4 h;
        h[0] = (_Float16)v.x; h[1] = (_Float16)v.y;
        h[2] = (_Float16)v.z; h[3] = (_Float16)v.w;
        int byte = (c4 * 8) ^ ((r & 7) << 4);
        *(f16x4*)((char*)sA + r * 256 + byte) = h;
    }
    // stage B: transpose W1 (128x64) -> sB[n][k]
    {
        int n = tid & 63, kq = tid >> 6;  // kq 0..3, 32 k each
        _Float16 tmp[32];
#pragma unroll
        for (int kk = 0; kk < 32; ++kk)
            tmp[kk] = (_Float16)W1[(size_t)(kq * 32 + kk) * H1 + n];
#pragma unroll
        for (int j = 0; j < 4; ++j) {
            int byte = ((kq * 32 + j * 8) * 2) ^ ((n & 7) << 4);
            *(f16x8*)((char*)sB + n * 256 + byte) = *(f16x8*)&tmp[j * 8];
        }
    }
    __syncthreads();
    int lane = tid & 63, w = tid >> 6;
    int lr = lane & 15, kg = lane >> 4;
    f32x4 acc[4] = {};
    int ar = w * 16 + lr;
    const char* pa = (const char*)sA + ar * 256;
    int axor = (ar & 7) << 4;
#pragma unroll
    for (int ks = 0; ks < 4; ++ks) {
        int kb = ks * 64 + kg * 16;      // byte offset of this lane's k-chunk
        f16x8 a = *(const f16x8*)(pa + (kb ^ axor));
#pragma unroll
        for (int nt = 0; nt < 4; ++nt) {
            int bn = nt * 16 + lr;
            f16x8 b = *(const f16x8*)((const char*)sB + bn * 256 + (kb ^ ((bn & 7) << 4)));
            acc[nt] = __builtin_amdgcn_mfma_f32_16x16x32_f16(a, b, acc[nt], 0, 0, 0);
        }
    }
    // C/D: col = lane&15, row = (lane>>4)*4 + reg   [m89-verified]
#pragma unroll
    for (int rg = 0; rg < 4; ++rg) {
        int R = row0 + w * 16 + kg * 4 + rg;
        if (R < N) {
            float dv = dinv[R];
#pragma unroll
            for (int nt = 0; nt < 4; ++nt)
                t1h[(size_t)R * H1 + nt * 16 + lr] = (_Float16)(acc[nt][rg] * dv);
        }
    }
}

// ---- MFMA GEMM layer 2: t2h(fp16) = (agg1h @ W2) * dinv ; M=64,N=32,K=64 ----
__global__ __launch_bounds__(256) void k_mgemm2(const _Float16* __restrict__ aggh,
        const float* __restrict__ W2, const float* __restrict__ dinv,
        _Float16* __restrict__ t2h, int N) {
    __shared__ _Float16 sA[64 * 64];    // 8 KB, row 128 B, swizzled
    __shared__ _Float16 sB[32 * 64];    // 4 KB, sB[n][k] = W2[k][n], swizzled
    int tid = threadIdx.x;
    int row0 = blockIdx.x * 64;
    // stage A (already fp16 + ReLU applied upstream)
#pragma unroll
    for (int i = 0; i < 2; ++i) {
        int idx8 = tid + 256 * i;        // 0..511 f16x8 chunks
        int r = idx8 >> 3, c8 = idx8 & 7;
        int row = row0 + r;
        f16x8 h = {};
        if (row < N) h = *(const f16x8*)&aggh[(size_t)row * H1 + c8 * 8];
        int byte = (c8 * 16) ^ ((r & 7) << 4);
        *(f16x8*)((char*)sA + r * 128 + byte) = h;
    }
    // stage B: transpose W2 (64x32) -> sB[n][k]
    {
        int n = tid & 31, kq = tid >> 5;  // kq 0..7, 8 k each
        _Float16 tmp[8];
#pragma unroll
        for (int kk = 0; kk < 8; ++kk)
            tmp[kk] = (_Float16)W2[(size_t)(kq * 8 + kk) * H2 + n];
        int byte = (kq * 16) ^ ((n & 7) << 4);
        *(f16x8*)((char*)sB + n * 128 + byte) = *(f16x8*)&tmp[0];
    }
    __syncthreads();
    int lane = tid & 63, w = tid >> 6;
    int lr = lane & 15, kg = lane >> 4;
    f32x4 acc[2] = {};
    int ar = w * 16 + lr;
    const char* pa = (const char*)sA + ar * 128;
    int axor = (ar & 7) << 4;
#pragma unroll
    for (int ks = 0; ks < 2; ++ks) {
        int kb = ks * 64 + kg * 16;
        f16x8 a = *(const f16x8*)(pa + (kb ^ axor));
#pragma unroll
        for (int nt = 0; nt < 2; ++nt) {
            int bn = nt * 16 + lr;
            f16x8 b = *(const f16x8*)((const char*)sB + bn * 128 + (kb ^ ((bn & 7) << 4)));
            acc[nt] = __builtin_amdgcn_mfma_f32_16x16x32_f16(a, b, acc[nt], 0, 0, 0);
        }
    }
#pragma unroll
    for (int rg = 0; rg < 4; ++rg) {
        int R = row0 + w * 16 + kg * 4 + rg;
        if (R < N) {
            float dv = dinv[R];
#pragma unroll
            for (int nt = 0; nt < 2; ++nt)
                t2h[(size_t)R * H2 + nt * 16 + lr] = (_Float16)(acc[nt][rg] * dv);
        }
    }
}

// ---- pull aggregation (fp16 table, fp32 accum)
//      FUSE: out = fp16(relu(acc*dinv)) ; else out = fp32(acc*dinv) ----
template <int LOGF2, bool FUSE>
__global__ __launch_bounds__(256) void k_aggh(const int* __restrict__ rowptr,
        const int* __restrict__ degi, const int* __restrict__ csr_src,
        const float* __restrict__ dinv, const __half2* __restrict__ tp,
        void* __restrict__ outv, int N) {
    const int F2 = 1 << LOGF2;
    int local = threadIdx.x >> LOGF2;
    int j = threadIdx.x & (F2 - 1);
    int n = blockIdx.x * (256 >> LOGF2) + local;
    if (n >= N) return;
    int start = rowptr[n];
    int deg = degi[n];
    float2 f = __half22float2(tp[((size_t)n << LOGF2) + j]);   // self term
    float ax = f.x, ay = f.y;
    int k = 0;
    for (; k + 4 <= deg; k += 4) {
        int s0 = csr_src[start + k + 0];
        int s1 = csr_src[start + k + 1];
        int s2 = csr_src[start + k + 2];
        int s3 = csr_src[start + k + 3];
        float2 f0 = __half22float2(tp[((size_t)s0 << LOGF2) + j]);
        float2 f1 = __half22float2(tp[((size_t)s1 << LOGF2) + j]);
        float2 f2 = __half22float2(tp[((size_t)s2 << LOGF2) + j]);
        float2 f3 = __half22float2(tp[((size_t)s3 << LOGF2) + j]);
        ax += f0.x + f1.x + f2.x + f3.x;
        ay += f0.y + f1.y + f2.y + f3.y;
    }
    for (; k < deg; ++k) {
        int s = csr_src[start + k];
        float2 f0 = __half22float2(tp[((size_t)s << LOGF2) + j]);
        ax += f0.x; ay += f0.y;
    }
    float dv = dinv[n];
    size_t idx = ((size_t)n << LOGF2) + j;
    if (FUSE) {
        ((__half2*)outv)[idx] =
            __floats2half2_rn(fmaxf(ax * dv, 0.f), fmaxf(ay * dv, 0.f));
    } else {
        ((float2*)outv)[idx] = make_float2(ax * dv, ay * dv);
    }
}

extern "C" void kernel_launch(void* const* d_in, const int* in_sizes, int n_in,
                              void* d_out, int out_size, void* d_ws, size_t ws_size,
                              hipStream_t stream) {
    const float* x  = (const float*)d_in[0];
    const int*   ei = (const int*)d_in[1];
    const float* W1 = (const float*)d_in[2];
    const float* W2 = (const float*)d_in[3];

    const int N = in_sizes[0] / DIN;   // 100000
    const int E = in_sizes[1] / 2;     // 1600000
    const int* src = ei;
    const int* dst = ei + E;

    const int NB    = (N + (1 << BSH) - 1) >> BSH;   // 391 buckets
    const int NBNCH = NB * NCH;                       // 200192
    const int chunk = (E + NCH - 1) / NCH;            // 3125

    // workspace layout (4-byte elems unless noted)
    float*    dinv    = (float*)d_ws;                     // N
    int*      degi    = (int*)(dinv + N);                 // N
    int*      rowptr  = degi + N;                         // N
    int*      H       = rowptr + N;                       // NB*NCH
    int*      partial = H + NBNCH;                        // 256
    int*      csr_src = partial + 256;                    // E
    _Float16* t1h     = (_Float16*)(csr_src + E);         // N*64 halves (12.8 MB)
    _Float16* agg1h   = t1h + (size_t)N * H1;             // N*64 halves (12.8 MB)
    _Float16* t2h     = t1h;                              // reuse after agg1h built
    float*    out     = (float*)d_out;                    // N*32 fp32
    int2*     ep      = (int2*)t1h;                       // E int2 (12.8 MB),
                                                          // consumed by k_csr before
                                                          // gemm1 writes t1h

    // --- counting-sort CSR build (no global atomics) ---
    k_hist<<<NCH, 256, 0, stream>>>(dst, H, E, NB, chunk);
    k_scan1<<<(NBNCH + 1023) / 1024, 256, 0, stream>>>(H, H, partial, NBNCH);
    k_scan2<<<1, 256, 0, stream>>>(partial, (NBNCH + 1023) / 1024);
    k_scan3b<<<(NBNCH + 255) / 256, 256, 0, stream>>>(H, partial, NBNCH);
    k_bsort<<<NCH, 256, 0, stream>>>(src, dst, H, ep, E, NB, chunk);
    k_csr<<<NB, 256, 0, stream>>>(ep, H, degi, rowptr, dinv, csr_src, E, N, NB);

    const int ntile = (N + 63) / 64;                 // 1563

    // --- layer 1 ---
    k_mgemm1<<<ntile, 256, 0, stream>>>(x, W1, dinv, t1h, N);
    k_aggh<5, true><<<(N + 7) / 8, 256, 0, stream>>>(rowptr, degi, csr_src, dinv,
                                                     (const __half2*)t1h, agg1h, N);

    // --- layer 2 ---
    k_mgemm2<<<ntile, 256, 0, stream>>>(agg1h, W2, dinv, t2h, N);
    k_aggh<4, false><<<(N + 15) / 16, 256, 0, stream>>>(rowptr, degi, csr_src, dinv,
                                                        (const __half2*)t2h, out, N);
}